// Round 6
// baseline (55.169 us; speedup 1.0000x reference)
//
#include <hip/hip_runtime.h>

// Mutual information of an 8192x8192 fp32 contingency table.
// MI = sum_{C>0} C*log2(C) - sum_i mx_i*log2(mx_i) - sum_j my_j*log2(my_j)
// (exact rewrite: zero entries contribute nothing to the masked sums, so the
//  masked row/col sums equal the full marginals).
//
// 2-node graph:
//   node 1 (mi_main): round-2 geometry (32x32 grid, 256x256 tiles, proven
//     fastest tie). Block (0,0) also zeroes the acc/cnt cells used by node 2
//     (visible at kernel boundary). NO fences (round 3: fence storms = 6x).
//   node 2 (mi_ep): 64 blocks; b<32 rows / b>=32 cols. Each block folds its
//     32 panel partials per marginal, computes -x*log2(x), folds 16 s1 cells,
//     then contributes via a FENCE-FREE last-arriver protocol:
//       old = atomicAdd(acc, p)   // consuming old forces vmcnt drain ->
//                                 // the add is globally complete
//       prev = atomicAdd(cnt, 1)  // completion-before-increment chain
//       prev == 63  ->  all 64 adds complete -> atomic-read acc, write out.
//     Device-scope atomics are coherent across XCDs without fences [m20].

#define NROWS 8192
#define MCOLS 8192

__inline__ __device__ float waveReduceSum(float v) {
    #pragma unroll
    for (int off = 32; off > 0; off >>= 1)
        v += __shfl_xor(v, off, 64);
    return v;
}

__global__ __launch_bounds__(256) void mi_main(const float* __restrict__ C,
                                               float* __restrict__ P_rows,
                                               float* __restrict__ P_cols,
                                               float* __restrict__ s1_arr,
                                               float* __restrict__ acc,
                                               int*   __restrict__ cnt) {
    const int bx = blockIdx.x;            // column-panel 0..31
    const int by = blockIdx.y;            // row-panel 0..31
    const int tcol = bx * 256, trow = by * 256;
    const int tid  = threadIdx.x;
    const int lane = tid & 63;
    const int wave = tid >> 6;

    // zero node-2's protocol cells; visible to node 2 via kernel-boundary flush
    if (bx == 0 && by == 0 && tid == 0) { acc[0] = 0.f; cnt[0] = 0; }

    // lds_row[r][k]: bank = (r*33 + k) % 32 = (r + k) % 32 -> conflict-free
    __shared__ float lds_row[256][33];
    __shared__ float lds_col[4][256];
    __shared__ float lds_s1[4];

    float c0 = 0.f, c1 = 0.f, c2 = 0.f, c3 = 0.f;
    float s1_local = 0.f;

    const float* base = C + (size_t)trow * MCOLS + tcol + lane * 4;

    #pragma unroll 8
    for (int i = 0; i < 64; ++i) {
        const int r = i * 4 + wave;       // tile row handled by this wave
        const float4 v = *reinterpret_cast<const float4*>(base + (size_t)r * MCOLS);

        // masked C*log2(C)
        float t0 = (v.x > 0.f) ? v.x * __log2f(v.x) : 0.f;
        float t1 = (v.y > 0.f) ? v.y * __log2f(v.y) : 0.f;
        float t2 = (v.z > 0.f) ? v.z * __log2f(v.z) : 0.f;
        float t3 = (v.w > 0.f) ? v.w * __log2f(v.w) : 0.f;
        s1_local += (t0 + t1) + (t2 + t3);

        // register column accumulators (thread sees the same 4 cols each iter)
        c0 += v.x; c1 += v.y; c2 += v.z; c3 += v.w;

        // row partial: fold upper half onto lower, stage 32 values in LDS
        float p = (v.x + v.y) + (v.z + v.w);
        p += __shfl_xor(p, 32, 64);
        if (lane < 32) lds_row[r][lane] = p;
    }

    // stage column partials
    lds_col[wave][lane * 4 + 0] = c0;
    lds_col[wave][lane * 4 + 1] = c1;
    lds_col[wave][lane * 4 + 2] = c2;
    lds_col[wave][lane * 4 + 3] = c3;

    // s1 partial per wave (one butterfly per kernel, not per iteration)
    const float s1w = waveReduceSum(s1_local);
    if (lane == 0) lds_s1[wave] = s1w;

    __syncthreads();

    // transposed row reduce: thread t owns tile-row t (2-way alias = free)
    float rs = 0.f;
    #pragma unroll
    for (int k = 0; k < 32; ++k) rs += lds_row[tid][k];
    P_rows[(size_t)bx * NROWS + trow + tid] = rs;

    // column reduce: thread t owns tile-col t
    const float cs = (lds_col[0][tid] + lds_col[1][tid]) +
                     (lds_col[2][tid] + lds_col[3][tid]);
    P_cols[(size_t)by * MCOLS + tcol + tid] = cs;

    if (tid == 0)
        s1_arr[by * 32 + bx] = (lds_s1[0] + lds_s1[1]) + (lds_s1[2] + lds_s1[3]);
}

// 64 blocks: b<32 -> row marginals, b>=32 -> col marginals (32 panels each).
// Each block also folds 16 s1 cells. Fence-free last-arriver finalization.
__global__ __launch_bounds__(256) void mi_ep(const float* __restrict__ P_rows,
                                             const float* __restrict__ P_cols,
                                             const float* __restrict__ s1_arr,
                                             float* __restrict__ acc,
                                             int*   __restrict__ cnt,
                                             float* __restrict__ out) {
    const int b    = blockIdx.x;
    const int tid  = threadIdx.x;
    const int lane = tid & 63;
    const int wave = tid >> 6;

    const float* P = (b < 32) ? P_rows : P_cols;
    const int idx  = ((b & 31) << 8) + tid;      // marginal index 0..8191

    float x = 0.f;
    #pragma unroll
    for (int k = 0; k < 32; ++k) x += P[(size_t)k * 8192 + idx];

    float a = (x > 0.f) ? -x * __log2f(x) : 0.f;   // entropy enters negated
    if (tid < 16) a += s1_arr[b * 16 + tid];       // distributed s1 sum (1024)

    a = waveReduceSum(a);
    __shared__ float lds[4];
    if (lane == 0) lds[wave] = a;
    __syncthreads();

    if (tid == 0) {
        const float p = (lds[0] + lds[1]) + (lds[2] + lds[3]);
        const float old = atomicAdd(acc, p);
        // consume `old` -> compiler emits s_waitcnt vmcnt(0): our add has
        // COMPLETED at the coherence point before the counter increment below
        __asm__ volatile("" :: "v"(old));
        const int prev = atomicAdd(cnt, 1);
        if (prev == 63) {
            // all 64 acc-adds complete (each was drained before its cnt inc)
            out[0] = atomicAdd(acc, 0.0f);   // coherent read of the total
        }
    }
}

extern "C" void kernel_launch(void* const* d_in, const int* in_sizes, int n_in,
                              void* d_out, int out_size, void* d_ws, size_t ws_size,
                              hipStream_t stream) {
    const float* C = (const float*)d_in[0];
    float* ws      = (float*)d_ws;
    float* P_rows  = ws;                    // 32*8192 = 1 MB
    float* P_cols  = ws + 262144;           // 32*8192 = 1 MB
    float* s1_arr  = ws + 524288;           // 1024
    float* acc     = ws + 525312;           // 1 float
    int*   cnt     = (int*)(ws + 525313);   // 1 int
    // every cell is written-before-read every call -> no memset node

    dim3 grid(MCOLS / 256, NROWS / 256);    // 32 x 32 = 1024 blocks
    mi_main<<<grid, 256, 0, stream>>>(C, P_rows, P_cols, s1_arr, acc, cnt);
    mi_ep<<<64, 256, 0, stream>>>(P_rows, P_cols, s1_arr, acc, cnt, (float*)d_out);
}